// Round 1
// baseline (1344.605 us; speedup 1.0000x reference)
//
#include <hip/hip_runtime.h>

#define KSZ  5
#define PADK 2
#define NB   16
#define NC   3
#define NH   256
#define NW   256
#define TW   32
#define TH   32
#define TS   (TW + 2 * PADK)   // 36
#define NTAP (KSZ * KSZ)       // 25
#define NWT  (NC * NTAP)       // 75

__global__ __launch_bounds__(256, 2)
void highorder_fused(const float* __restrict__ x,
                     const float* __restrict__ cw,
                     const float* __restrict__ cb,
                     float* __restrict__ out)
{
    __shared__ float xt[NC * TS * TS];   // 15552 B

    const int tid = threadIdx.x;
    const int bx  = blockIdx.x % (NW / TW);
    const int by  = (blockIdx.x / (NW / TW)) % (NH / TH);
    const int b   = blockIdx.x / ((NW / TW) * (NH / TH));
    const int bw0 = bx * TW;
    const int bh0 = by * TH;

    const float* xb = x + (size_t)b * NC * NH * NW;

    // Stage x tile + halo (zero-padded at image borders)
    for (int idx = tid; idx < NC * TS * TS; idx += 256) {
        int c  = idx / (TS * TS);
        int r  = idx - c * (TS * TS);
        int yy = r / TS;
        int xx = r - yy * TS;
        int gh = bh0 + yy - PADK;
        int gw = bw0 + xx - PADK;
        float v = 0.0f;
        if ((unsigned)gh < NH && (unsigned)gw < NW)
            v = xb[c * NH * NW + gh * NW + gw];
        xt[idx] = v;
    }
    __syncthreads();

    // Each thread: 4 pixels, sequentially (keep code/regs to one pixel's worth)
    #pragma unroll 1
    for (int p = tid; p < TW * TH; p += 256) {
        const int py = p >> 5;    // p / 32
        const int px = p & 31;    // p % 32

        // Load the 3x5x5 neighborhood into registers (static indexing only)
        float nb[NWT];
        #pragma unroll
        for (int c = 0; c < NC; ++c)
            #pragma unroll
            for (int i = 0; i < KSZ; ++i)
                #pragma unroll
                for (int j = 0; j < KSZ; ++j)
                    nb[c * NTAP + i * KSZ + j] =
                        xt[c * TS * TS + (py + i) * TS + (px + j)];

        // Phase 1: 25 per-pixel weights = conv(x) + bias.
        // cw index is wave-uniform -> scalar loads -> SGPR operand of v_fma.
        float wgt[NTAP];
        #pragma unroll
        for (int k = 0; k < NTAP; ++k) {
            float acc = cb[k];
            #pragma unroll
            for (int t = 0; t < NWT; ++t)
                acc = fmaf(cw[k * NWT + t], nb[t], acc);
            wgt[k] = acc;
        }

        // Phase 2: dynamic aggregation + residual (center tap = i=j=2 -> 12)
        const int h = bh0 + py;
        const int w = bw0 + px;
        float* ob = out + (size_t)b * NC * NH * NW + (size_t)h * NW + w;
        #pragma unroll
        for (int c = 0; c < NC; ++c) {
            float acc = nb[c * NTAP + 12];
            #pragma unroll
            for (int k = 0; k < NTAP; ++k)
                acc = fmaf(wgt[k], nb[c * NTAP + k], acc);
            ob[(size_t)c * NH * NW] = acc;
        }
    }
}

extern "C" void kernel_launch(void* const* d_in, const int* in_sizes, int n_in,
                              void* d_out, int out_size, void* d_ws, size_t ws_size,
                              hipStream_t stream)
{
    const float* x  = (const float*)d_in[0];
    const float* cw = (const float*)d_in[1];
    const float* cb = (const float*)d_in[2];
    float* out      = (float*)d_out;

    dim3 grid(NB * (NH / TH) * (NW / TW));   // 16 * 8 * 8 = 1024 blocks
    highorder_fused<<<grid, 256, 0, stream>>>(x, cw, cb, out);
}

// Round 2
// 57.805 us; speedup vs baseline: 23.2609x; 23.2609x over previous
//
#include <hip/hip_runtime.h>

#define KSZ    5
#define PADK   2
#define NBATCH 16
#define NC     3
#define NH     256
#define NW     256
#define TW     16
#define TH     16
#define TSH    20            // tile rows incl. halo
#define TSW    24            // padded row stride (cols 0..19 valid)
#define PLANE  (TSH * TSW)   // 480
#define NTAP   25
#define NWT    75
#define CWLD   32            // padded row length of transposed weights

// cwT[t][k] = cw[k][t], rows padded to 32 floats for wide scalar loads
__global__ void transpose_cw_k(const float* __restrict__ cw,
                               float* __restrict__ cwT)
{
    int idx = threadIdx.x + blockIdx.x * 256;
    if (idx < NWT * CWLD) {
        int t = idx / CWLD;
        int k = idx - t * CWLD;
        cwT[idx] = (k < NTAP) ? cw[k * NWT + t] : 0.0f;
    }
}

__global__ __launch_bounds__(256, 4)
void highorder2(const float* __restrict__ x,
                const float* __restrict__ cwT,
                const float* __restrict__ cb,
                float* __restrict__ out)
{
    __shared__ float xt[NC * PLANE];   // 5760 B

    const int tid = threadIdx.x;
    const int bx  = blockIdx.x % (NW / TW);
    const int by  = (blockIdx.x / (NW / TW)) % (NH / TH);
    const int b   = blockIdx.x / ((NW / TW) * (NH / TH));
    const int bw0 = bx * TW;
    const int bh0 = by * TH;

    const float* xb = x + (size_t)b * NC * NH * NW;

    // Stage tile + halo (valid cols 0..19; cols 20..23 are stride padding)
    for (int i = tid; i < NC * PLANE; i += 256) {
        int c  = i / PLANE;
        int r  = i - c * PLANE;
        int yy = r / TSW;
        int xx = r - yy * TSW;
        int gh = bh0 + yy - PADK;
        int gw = bw0 + xx - PADK;
        float v = 0.0f;
        if (xx < TW + 2 * PADK && (unsigned)gh < NH && (unsigned)gw < NW)
            v = xb[c * NH * NW + gh * NW + gw];
        xt[i] = v;
    }
    __syncthreads();

    const int px = tid & (TW - 1);   // 0..15
    const int py = tid >> 4;         // 0..15
    const float* base = &xt[py * TSW + px];

    // Phase 1: 25 per-pixel weights. acc[k] += cwT[t][k] * nb[t]
    // cwT index is wave-uniform -> s_load; nb streams via ds_read_b32.
    float acc[NTAP];
    #pragma unroll
    for (int k = 0; k < NTAP; ++k) acc[k] = cb[k];

    #pragma unroll 1
    for (int c = 0; c < NC; ++c) {
        const float* bc = base + c * PLANE;
        const float* wc = cwT + c * NTAP * CWLD;
        #pragma unroll
        for (int i = 0; i < KSZ; ++i) {
            #pragma unroll
            for (int j = 0; j < KSZ; ++j) {
                float v = bc[i * TSW + j];
                const float* w = wc + (i * KSZ + j) * CWLD;
                #pragma unroll
                for (int k = 0; k < NTAP; ++k)
                    acc[k] = fmaf(w[k], v, acc[k]);
            }
        }
    }

    // Phase 2: dynamic aggregation + residual (center tap i=j=2)
    float* ob = out + (size_t)b * NC * NH * NW
                    + (size_t)(bh0 + py) * NW + (bw0 + px);
    #pragma unroll 1
    for (int c = 0; c < NC; ++c) {
        const float* bc = base + c * PLANE;
        float s = bc[2 * TSW + 2];   // residual x
        #pragma unroll
        for (int i = 0; i < KSZ; ++i)
            #pragma unroll
            for (int j = 0; j < KSZ; ++j)
                s = fmaf(acc[i * KSZ + j], bc[i * TSW + j], s);
        ob[(size_t)c * NH * NW] = s;
    }
}

extern "C" void kernel_launch(void* const* d_in, const int* in_sizes, int n_in,
                              void* d_out, int out_size, void* d_ws, size_t ws_size,
                              hipStream_t stream)
{
    const float* x  = (const float*)d_in[0];
    const float* cw = (const float*)d_in[1];
    const float* cb = (const float*)d_in[2];
    float* out      = (float*)d_out;
    float* cwT      = (float*)d_ws;   // 75*32*4 = 9600 B

    transpose_cw_k<<<(NWT * CWLD + 255) / 256, 256, 0, stream>>>(cw, cwT);

    dim3 grid(NBATCH * (NH / TH) * (NW / TW));   // 16*16*16 = 4096 blocks
    highorder2<<<grid, 256, 0, stream>>>(x, cwT, cb, out);
}